// Round 1
// 199.107 us; speedup vs baseline: 1.0079x; 1.0079x over previous
//
#include <hip/hip_runtime.h>

#define NROW 6
#define NCOL 6
#define BATCH 1024
#define NSITE 36

// LDS bank-conflict swizzle: XOR dword-addr bits [4:2] with bits [7:5].
// Preserves bits [1:0]; constant within any aligned 4-dword window; SWZ(0)==0.
__device__ __forceinline__ int SWZ(int a) { return a ^ (((a >> 5) & 7) << 2); }

// Wave-uniform scalar-memory pointer: address_space(4) = AMDGPU constant.
// Scalar float loads at uniform offsets merge into s_load_dwordx4/x16 (SMEM
// pipe, one fetch per wave) — R12 proved this path (534 -> 372 us).
typedef const float __attribute__((address_space(4))) * fcp;

// Pre-transpose T[site][spin][u=x][r=gp][d=z][l=g] into
// Tm[(site*2+spin)*256 + (gp*4+z)*16 + (g*4+x)]  (73,728 B in d_ws).
__global__ void peps_reorder_kernel(const float* __restrict__ T,
                                    float* __restrict__ Tm)
{
    int idx = blockIdx.x * 256 + threadIdx.x;   // [0, 18432)
    if (idx >= NSITE * 2 * 256) return;
    int i  = idx & 15;          // i = g*4 + x
    int o  = (idx >> 4) & 15;   // o = gp*4 + z
    int sp = (idx >> 8) & 1;
    int st = idx >> 9;
    int g = i >> 2, x = i & 3, gp = o >> 2, z = o & 3;
    Tm[idx] = T[st * 512 + sp * 256 + x * 64 + gp * 16 + z * 4 + g];
}

// One step body, 2 SPECTATORS PER THREAD (u = 2t, 2t+1), fully specialized,
// one divergent branch. R18 change vs R17 (4 spect x 256 thr): 512 threads x
// 2 spectators. Same total FMA issue and same LDS bytes (b128 -> b64 pairs),
// but 8 waves/block x 2 blocks/CU = 4 waves/SIMD (was 2) -> doubles latency
// hiding for the ds_read->FMA-chain->barrier critical path that caused the
// 55% non-VALU stall (VALUBusy 45%, Occupancy 21% in R17 counters).
// Spectator pairs stay LDS-contiguous for all ZS==4 and C0 steps (lowb>=2
// there, and SWZ preserves addr bits [1:0] so float2 is safe and 8B-aligned).
template<int GIN, int GOUT, int XS, int ZS, bool C0>
__device__ __forceinline__ void do_step2(float* __restrict__ W, const fcp Msf,
                                         const int* __restrict__ A, int p4c,
                                         bool act)
{
    if (!act) return;
    float in_s[2][16];           // [spectator][g*4+x]
    // ---- read phase ----
    if (C0) {                    // GIN==1; x (or z) is the low address digit
        if (XS == 4) {
            #pragma unroll
            for (int i = 0; i < 2; ++i) {
                float4 q = *(const float4*)&W[A[i]];
                in_s[i][0] = q.x; in_s[i][1] = q.y;
                in_s[i][2] = q.z; in_s[i][3] = q.w;
            }
        } else {
            #pragma unroll
            for (int i = 0; i < 2; ++i) in_s[i][0] = W[A[i]];
        }
    } else if (ZS == 4) {        // spectator pair contiguous at A[x]
        #pragma unroll
        for (int g = 0; g < GIN; ++g)
            #pragma unroll
            for (int x = 0; x < XS; ++x) {
                float2 q = *(const float2*)&W[A[x] + g * 4096];
                in_s[0][g*4+x] = q.x; in_s[1][g*4+x] = q.y;
            }
    } else {                     // row5 c>=1: scattered scalars (tiny work)
        #pragma unroll
        for (int g = 0; g < GIN; ++g)
            #pragma unroll
            for (int x = 0; x < XS; ++x)
                #pragma unroll
                for (int i = 0; i < 2; ++i)
                    in_s[i][g*4+x] = W[SWZ(x * p4c + A[i]) + g * 4096];
    }
    // ---- compute + write (in-place; same address set) ----
    #pragma unroll
    for (int gp = 0; gp < GOUT; ++gp) {
        float a[ZS][2];
        #pragma unroll
        for (int z = 0; z < ZS; ++z) {
            const int mb = (gp * 4 + z) * 16;
            #pragma unroll
            for (int i = 0; i < 2; ++i) a[z][i] = 0.f;
            #pragma unroll
            for (int g = 0; g < GIN; ++g)
                #pragma unroll
                for (int x = 0; x < XS; ++x) {
                    const float m = Msf[mb + g * 4 + x];
                    #pragma unroll
                    for (int i = 0; i < 2; ++i)
                        a[z][i] += m * in_s[i][g*4+x];
                }
        }
        if (C0 && ZS == 4) {
            #pragma unroll
            for (int i = 0; i < 2; ++i)
                *(float4*)&W[A[i] + gp * 4096] =
                    make_float4(a[0][i], a[1][i], a[2][i], a[3][i]);
        } else if (ZS == 4) {
            #pragma unroll
            for (int z = 0; z < 4; ++z)
                *(float2*)&W[A[z] + gp * 4096] =
                    make_float2(a[z][0], a[z][1]);
        } else if (C0) {         // row5 c0: z collapses, base address
            #pragma unroll
            for (int i = 0; i < 2; ++i) W[A[i] + gp * 4096] = a[0][i];
        } else {                 // row5 c>=1
            #pragma unroll
            for (int i = 0; i < 2; ++i) W[SWZ(A[i]) + gp * 4096] = a[0][i];
        }
    }
}

// Fixed-slot in-place contraction (verified R8..R17 algebra): state index =
// g*4096 + sum_j slot_j*4^j; step (row,c) reads up-bond x from slot c and
// writes down-bond z back into the same slot. ONE barrier/step. State in LDS
// (64 KB, swizzled). scount=1 steps: (0,0)'s stray spectator writes land in
// W[4..7](+gp*4096), fully overwritten by step (0,1) before (0,2) reads
// them; (5,5) is last (only W[0] read). 512 threads x 2 spectators; 2
// blocks/CU (LDS-bound), 16 waves/CU = 4/SIMD for latency hiding.
__global__ __launch_bounds__(512, 4)
void peps_amp_kernel(const int* __restrict__ X, const float* __restrict__ Tm,
                     float* __restrict__ out)
{
    __shared__ float W[16384];   // 65536 B exactly (4^7 fixed-slot state)

    const int b = blockIdx.x;
    const int t = threadIdx.x;
    const int u0 = 2 * t;        // this thread's spectators: u0, u0+1
    const int* xrow = X + b * NSITE;

    // PHYS=2: pack the 36 spins into one scalar 64-bit mask (SGPR-resident
    // so every Tm address below is provably wave-uniform).
    unsigned long long sm = 0ull;
    const int4* xp = (const int4*)xrow;
    #pragma unroll
    for (int k = 0; k < 9; ++k) {
        int4 v = xp[k];
        sm |= ((unsigned long long)(v.x & 1)) << (4 * k + 0);
        sm |= ((unsigned long long)(v.y & 1)) << (4 * k + 1);
        sm |= ((unsigned long long)(v.z & 1)) << (4 * k + 2);
        sm |= ((unsigned long long)(v.w & 1)) << (4 * k + 3);
    }
    {
        unsigned lo = __builtin_amdgcn_readfirstlane((int)(sm & 0xffffffffull));
        unsigned hi = __builtin_amdgcn_readfirstlane((int)(sm >> 32));
        sm = ((unsigned long long)hi << 32) | lo;
    }

    if (t == 0) W[0] = 1.0f;     // seed (SWZ(0)==0); covered by step-0 barrier

    int step = 0;
    for (int row = 0; row < NROW; ++row) {
        const int xs = (row == 0) ? 1 : 4;          // up-bond size
        const int zs = (row == NROW - 1) ? 1 : 4;   // down-bond size
        for (int c = 0; c < NCOL; ++c, ++step) {
            const int lowb  = (zs == 4) ? 2 * c : 0;
            const int highb = (xs == 4) ? 2 * (5 - c) : 0;
            const int scount = 1 << (lowb + highb);
            const int p4c = 1 << (2 * c);
            const int lowmask = (1 << lowb) - 1;
            const bool act = (u0 < scount);

            // uniform scalar: spin bit + M base for this step (SMEM pointer)
            const int spin = (int)((sm >> step) & 1ull);
            const fcp Msf = (fcp)(unsigned long long)
                (const void*)(Tm + (size_t)(step * 2 + spin) * 256);

            __syncthreads();     // the ONLY barrier per step

            // per-thread LDS addresses (pair-aligned where vectorized)
            int A[4];
            if (c == 0) {
                #pragma unroll
                for (int i = 0; i < 2; ++i) A[i] = SWZ(8 * t + 4 * i);
            } else if (zs == 4) {
                const int mr0 = ((u0 >> lowb) << (2 * c + 2)) | (u0 & lowmask);
                #pragma unroll
                for (int d = 0; d < 4; ++d) A[d] = SWZ(d * p4c + mr0);
            } else {             // row5 c>=1: per-spectator bases, unswizzled
                #pragma unroll
                for (int i = 0; i < 2; ++i) A[i] = (u0 + i) << (2 * c + 2);
            }

            // uniform 3x3 dispatch to branch-free specialized bodies
            if (row == 0) {
                if (c == 0)            do_step2<1,4,1,4,true >(W, Msf, A, p4c, act);
                else if (c < NCOL - 1) do_step2<4,4,1,4,false>(W, Msf, A, p4c, act);
                else                   do_step2<4,1,1,4,false>(W, Msf, A, p4c, act);
            } else if (row < NROW - 1) {
                if (c == 0)            do_step2<1,4,4,4,true >(W, Msf, A, p4c, act);
                else if (c < NCOL - 1) do_step2<4,4,4,4,false>(W, Msf, A, p4c, act);
                else                   do_step2<4,1,4,4,false>(W, Msf, A, p4c, act);
            } else {
                if (c == 0)            do_step2<1,4,4,1,true >(W, Msf, A, p4c, act);
                else if (c < NCOL - 1) do_step2<4,4,4,1,false>(W, Msf, A, p4c, act);
                else                   do_step2<4,1,4,1,false>(W, Msf, A, p4c, act);
            }
        }
    }
    __syncthreads();
    // after (5,5): only g'=0, z=0, u=0 live -> the amplitude sits at W[0]
    if (t == 0) out[b] = W[0];
}

extern "C" void kernel_launch(void* const* d_in, const int* in_sizes, int n_in,
                              void* d_out, int out_size, void* d_ws, size_t ws_size,
                              hipStream_t stream) {
    const int*   X  = (const int*)d_in[0];     // x: [1024, 36] int32
    const float* Tg = (const float*)d_in[1];   // T: [6,6,2,4,4,4,4] fp32
    float* out = (float*)d_out;                // reference output: float32
    float* Tm  = (float*)d_ws;                 // 73,728 B scratch
    (void)in_sizes; (void)n_in; (void)ws_size; (void)out_size;
    peps_reorder_kernel<<<dim3(72), dim3(256), 0, stream>>>(Tg, Tm);
    peps_amp_kernel<<<dim3(BATCH), dim3(512), 0, stream>>>(X, Tm, out);
}